// Round 16
// baseline (82.198 us; speedup 1.0000x reference)
//
#include <hip/hip_runtime.h>
#include <hip/hip_bf16.h>

#define H_ 256
#define W_ 256
#define C_ 128
#define NBPOS 1024   // N * 16 * 16 block positions
#define NACT 512

typedef __bf16 bf16x8 __attribute__((ext_vector_type(8)));
typedef float f32x4 __attribute__((ext_vector_type(4)));

// workspace layout (bytes)
#define SCALE_OFF 294912
#define SHIFT_OFF 295424
#define INACT_OFF 295936

// Blocks 0..575: weight repack fp32 HWIO -> bf16 [tap][cin8][cout][8].
// Block 576: BN fold + inactive-block list (bitmap + compaction).
__global__ void prep_kernel(const float* __restrict__ w, const float* __restrict__ b,
                            const float* __restrict__ gamma, const float* __restrict__ beta,
                            const float* __restrict__ mean, const float* __restrict__ var,
                            const int* __restrict__ active,
                            __bf16* __restrict__ wprep, float* __restrict__ scale,
                            float* __restrict__ shift, int* __restrict__ inact) {
  int blk = blockIdx.x, tid = threadIdx.x;
  if (blk < 576) {
    int o = blk * 256 + tid;
    int j = o & 7, cout = (o >> 3) & 127, k8 = (o >> 10) & 15, tap = o >> 14;
    wprep[o] = (__bf16)w[((size_t)tap * 128 + k8 * 8 + j) * 128 + cout];
    return;
  }
  __shared__ unsigned mask[32];
  __shared__ int cnt;
  if (tid < 32) mask[tid] = 0u;
  if (tid == 0) cnt = 0;
  __syncthreads();
  for (int i = tid; i < NACT; i += 256) {
    int a = active[i];
    atomicOr(&mask[a >> 5], 1u << (a & 31));
  }
  if (tid < 128) {
    float s = gamma[tid] * rsqrtf(var[tid] + 1e-3f);
    scale[tid] = s;
    shift[tid] = (b[tid] - mean[tid]) * s + beta[tid];
  }
  __syncthreads();
  for (int p = tid; p < NBPOS; p += 256) {
    if (!((mask[p >> 5] >> (p & 31)) & 1u)) {
      int q = atomicAdd(&cnt, 1);
      inact[q] = p;   // order nondeterministic; disjoint coverage is what matters
    }
  }
}

// ONE main kernel, 3072 wgs, 2 conv : 1 copy interleave. The conv path is
// re-registered for OCCUPANCY (the measured cap: 128 regs/wave -> 16 waves/CU,
// occupancy 34%, everything idle -> latency-bound). Wave tile 2Mx4N:
// acc = 32 AGPR, ~85 unified regs -> 20-24 waves/CU.
//   idx%3==2 -> copy wg: stream HALF (64 KB) of inactive block inact[k>>1],
//               row-half k&1 (k = idx/3). Plain loads (L3-warm), NT stores.
//   else     -> conv wg j=(idx/3)*2+idx%3 (0..2047): M-QUARTER of active
//               block active[j>>2]: output rows (j&3)*4..+4, all 128 couts.
//               K=1152 implicit GEMM, fence-free K-loop (B direct from L1/L2,
//               identical addresses across waves), A patch 6x18px x 64ch bf16
//               in LDS (13.8 KB), XOR-swizzled, two channel halves.
__global__ __launch_bounds__(256, 5) void main_kernel(
    const float* __restrict__ x, const __bf16* __restrict__ wprep,
    const float* __restrict__ scale, const float* __restrict__ shift,
    const int* __restrict__ active, const int* __restrict__ inact,
    float* __restrict__ y) {
  __shared__ unsigned char ldsA[108 * 128];   // 6*18 px x 64ch bf16 = 13824 B

  const int idx = blockIdx.x;
  const int tid = threadIdx.x;

  if (idx % 3 == 2) {
    // ---- copy path: half of an inactive block ----
    const int k = idx / 3;                    // 0..1023
    const int cid = inact[k >> 1];
    const int ch = k & 1;
    const int cn = cid >> 8, cy = (cid >> 4) & 15, cx = cid & 15;
    const size_t base4 = ((((size_t)cn * H_ + cy * 16 + ch * 8) * W_ + cx * 16) * C_) >> 2;
    const f32x4* __restrict__ xs = (const f32x4*)x;
    f32x4* __restrict__ ys = (f32x4*)y;
#pragma unroll 4
    for (int i = 0; i < 16; ++i) {            // 8 rows x 512 f32x4 = 64 KB
      int lin = (i << 8) + tid;
      size_t i4 = base4 + (size_t)(lin >> 9) * (W_ * C_ / 4) + (lin & 511);
      f32x4 v = xs[i4];
      __builtin_nontemporal_store(v, &ys[i4]);
    }
    return;
  }

  // ---- conv path: one M-quarter (4 output rows x 16 cols) ----
  const int j = (idx / 3) * 2 + (idx % 3);    // 0..2047
  const int lane = tid & 63;
  const int wid = tid >> 6;
  const int wm = wid >> 1, wn = wid & 1;      // 2x2 wave grid (M x N)
  const int aid = active[j >> 2];
  const int q = j & 3;                        // M-quarter: output rows q*4..q*4+3
  const int bn = aid >> 8, by = (aid >> 4) & 15, bx = aid & 15;
  const int h0 = by * 16, w0 = bx * 16;
  const int hq = h0 + q * 4;                  // patch row origin (rows hq..hq+5)
  const float* xb = x + (size_t)bn * (H_ * W_ * C_);

  f32x4 acc[2][4];
  f32x4 zero = {0.f, 0.f, 0.f, 0.f};
#pragma unroll
  for (int i = 0; i < 2; ++i)
#pragma unroll
    for (int jj = 0; jj < 4; ++jj) acc[i][jj] = zero;

  const bf16x8* __restrict__ wq = (const bf16x8*)wprep;  // 16B fragment units
  const int koff = (lane >> 4) * 16;          // byte offset of k-oct within 32ch
  // B-frag base (16B units): tile*512 + (lane>>4)*128 + cout; cout = wn*64+nb*16+(lane&15)
  const int sbl = ((lane >> 4) << 7) + (wn << 6) + (lane & 15);

  auto stage = [&](int half) {                // 6x18 px x 64ch -> bf16 LDS, XOR-swizzled
    for (int u = tid; u < 108 * 8; u += 256) {
      int s = u >> 3, c8 = u & 7;             // s = pr*18 + col
      int pr = s / 18, col = s - pr * 18;
      int hs = hq + pr, wsp = w0 + col;
      float4 f0 = make_float4(0.f, 0.f, 0.f, 0.f), f1 = f0;
      if (hs < H_ && wsp < W_) {
        const float* p = xb + (size_t)(hs * W_ + wsp) * C_ + half * 64 + c8 * 8;
        f0 = *(const float4*)p;
        f1 = *(const float4*)(p + 4);
      }
      bf16x8 v;
      v[0] = (__bf16)f0.x; v[1] = (__bf16)f0.y; v[2] = (__bf16)f0.z; v[3] = (__bf16)f0.w;
      v[4] = (__bf16)f1.x; v[5] = (__bf16)f1.y; v[6] = (__bf16)f1.z; v[7] = (__bf16)f1.w;
      int lin = s * 128 + c8 * 16;
      *(bf16x8*)(&ldsA[lin ^ ((s & 7) << 4)]) = v;
    }
  };

  for (int half = 0; half < 2; ++half) {
    if (half) __syncthreads();                // all waves done reading half 0
    stage(half);
    __syncthreads();                          // ldsA staged; K-loop is fence-free

#pragma unroll 3
    for (int ks = 0; ks < 18; ++ks) {
      int tap = ks >> 1, kch = ks & 1;
      int dyv = tap / 3, dxv = tap - dyv * 3;
      int tile = tap * 4 + half * 2 + kch;

      bf16x8 a[2];
#pragma unroll
      for (int mi = 0; mi < 2; ++mi) {
        int srow = (wm * 2 + mi + dyv) * 18 + dxv + (lane & 15);
        int lin = srow * 128 + kch * 64 + koff;
        a[mi] = *(const bf16x8*)(&ldsA[lin ^ ((srow & 7) << 4)]);
      }
      bf16x8 bfr[4];
      int sb = tile * 512 + sbl;
#pragma unroll
      for (int nb = 0; nb < 4; ++nb)
        bfr[nb] = wq[sb + nb * 16];           // L1-resident, shared across waves/wgs
#pragma unroll
      for (int mi = 0; mi < 2; ++mi)
#pragma unroll
        for (int nb = 0; nb < 4; ++nb)
          acc[mi][nb] = __builtin_amdgcn_mfma_f32_16x16x32_bf16(a[mi], bfr[nb], acc[mi][nb], 0, 0, 0);
    }
  }

  // epilogue: BN + ReLU + scatter (NT stores). D frag: col=lane&15 (cout),
  // row=(lane>>4)*4+reg (spatial col ox)
  const int colc = lane & 15;
  float sc[4], sh[4];
#pragma unroll
  for (int nb = 0; nb < 4; ++nb) {
    sc[nb] = scale[wn * 64 + nb * 16 + colc];
    sh[nb] = shift[wn * 64 + nb * 16 + colc];
  }
  float* yb = y + (((size_t)bn * H_ + hq) * W_ + w0) * C_;
#pragma unroll
  for (int mi = 0; mi < 2; ++mi) {
    int oy = wm * 2 + mi;                     // row within this wg's 4-row quarter
#pragma unroll
    for (int r = 0; r < 4; ++r) {
      int ox = (lane >> 4) * 4 + r;
      float* yr = yb + ((size_t)oy * W_ + ox) * C_;
#pragma unroll
      for (int nb = 0; nb < 4; ++nb) {
        float v = acc[mi][nb][r] * sc[nb] + sh[nb];
        __builtin_nontemporal_store(fmaxf(v, 0.f), &yr[wn * 64 + nb * 16 + colc]);
      }
    }
  }
}

extern "C" void kernel_launch(void* const* d_in, const int* in_sizes, int n_in,
                              void* d_out, int out_size, void* d_ws, size_t ws_size,
                              hipStream_t stream) {
  const float* x     = (const float*)d_in[0];
  const float* w     = (const float*)d_in[1];
  const float* b     = (const float*)d_in[2];
  const float* gamma = (const float*)d_in[3];
  const float* beta  = (const float*)d_in[4];
  const float* mean  = (const float*)d_in[5];
  const float* var   = (const float*)d_in[6];
  const int*   act   = (const int*)d_in[7];
  float* y = (float*)d_out;
  char* ws = (char*)d_ws;
  __bf16* wprep = (__bf16*)ws;
  float* scale = (float*)(ws + SCALE_OFF);
  float* shift = (float*)(ws + SHIFT_OFF);
  int* inact = (int*)(ws + INACT_OFF);

  prep_kernel<<<dim3(577), dim3(256), 0, stream>>>(w, b, gamma, beta, mean, var, act,
                                                   wprep, scale, shift, inact);
  main_kernel<<<dim3(3072), dim3(256), 0, stream>>>(x, wprep, scale, shift, act, inact, y);
}